// Round 6
// baseline (281.489 us; speedup 1.0000x reference)
//
#include <hip/hip_runtime.h>
#include <math.h>

// z_e (8,4096,256) f32, codebook (1024,256) f32. M=32768, D=256, K=1024.
// out (f32, concat): z_q[8388608] | similarity[33554432] | ids[32768] | loss[1]
#define SIM_OFF  8388608
#define IDS_OFF  41943040
#define LOSS_OFF 41975808

// ws float offsets
#define NE_OFF    0        // ne[1024]
#define RSE_OFF   1024     // 1/sqrt(ne)
#define SQNE_OFF  2048     // sqrt(ne)
#define RSZ_OFF   3072     // 1/sqrt(nz) [32768]
#define SQNZ_OFF  35840    // sqrt(nz)   [32768]
#define PART_OFF  68608    // [8192], ends at float 76800 = byte 307200
#define CBHI_BYTE 307200   // 1024x256 bf16 = 524288 B
#define CBLO_BYTE 831488   // = 307200 + 524288 (FIX: was 819200, overlapped hi rows 1000-1023)

typedef __attribute__((ext_vector_type(8))) short bf16x8;
typedef __attribute__((ext_vector_type(4))) float f32x4;

__device__ __forceinline__ unsigned short bf16_rne(float x) {
  unsigned u = __float_as_uint(x);
  unsigned r = u + 0x7FFFu + ((u >> 16) & 1u);
  return (unsigned short)(r >> 16);
}
__device__ __forceinline__ float bf16_to_f(unsigned short h) {
  return __uint_as_float((unsigned)h << 16);
}
__device__ __forceinline__ unsigned long long packkey(float d, int idx) {
  unsigned u = __float_as_uint(d);
  u ^= (u & 0x80000000u) ? 0xFFFFFFFFu : 0x80000000u;
  return ((unsigned long long)u << 32) | (unsigned)idx;
}

// ---- codebook: norms + hi/lo bf16 planes (wave per row) ----
__global__ __launch_bounds__(256) void cb_prep(const float* __restrict__ cb,
                                               float* __restrict__ ws) {
  int row = blockIdx.x * 4 + (threadIdx.x >> 6);
  int l = threadIdx.x & 63;
  float4 v = ((const float4*)cb)[row * 64 + l];
  float s = v.x * v.x + v.y * v.y + v.z * v.z + v.w * v.w;
  #pragma unroll
  for (int m = 1; m < 64; m <<= 1) s += __shfl_xor(s, m, 64);
  ushort4 hi, lo;
  hi.x = bf16_rne(v.x); lo.x = bf16_rne(v.x - bf16_to_f(hi.x));
  hi.y = bf16_rne(v.y); lo.y = bf16_rne(v.y - bf16_to_f(hi.y));
  hi.z = bf16_rne(v.z); lo.z = bf16_rne(v.z - bf16_to_f(hi.z));
  hi.w = bf16_rne(v.w); lo.w = bf16_rne(v.w - bf16_to_f(hi.w));
  ((ushort4*)((char*)ws + CBHI_BYTE))[row * 64 + l] = hi;
  ((ushort4*)((char*)ws + CBLO_BYTE))[row * 64 + l] = lo;
  if (l == 0) {
    ws[NE_OFF + row] = s;
    ws[RSE_OFF + row] = 1.0f / sqrtf(s);
    ws[SQNE_OFF + row] = sqrtf(s);
  }
}

// ---- z_e: norms + hi/lo bf16 planes into the z_q output region ----
__global__ __launch_bounds__(256) void ze_prep(const float* __restrict__ ze,
                                               float* __restrict__ ws,
                                               float* __restrict__ out) {
  int row = blockIdx.x * 4 + (threadIdx.x >> 6);
  int l = threadIdx.x & 63;
  float4 v = ((const float4*)ze)[(size_t)row * 64 + l];
  float s = v.x * v.x + v.y * v.y + v.z * v.z + v.w * v.w;
  #pragma unroll
  for (int m = 1; m < 64; m <<= 1) s += __shfl_xor(s, m, 64);
  ushort4 hi, lo;
  hi.x = bf16_rne(v.x); lo.x = bf16_rne(v.x - bf16_to_f(hi.x));
  hi.y = bf16_rne(v.y); lo.y = bf16_rne(v.y - bf16_to_f(hi.y));
  hi.z = bf16_rne(v.z); lo.z = bf16_rne(v.z - bf16_to_f(hi.z));
  hi.w = bf16_rne(v.w); lo.w = bf16_rne(v.w - bf16_to_f(hi.w));
  unsigned short* zehi = (unsigned short*)out;            // 16 MB
  unsigned short* zelo = (unsigned short*)out + 8388608;  // next 16 MB (exact fit in z_q region)
  ((ushort4*)zehi)[(size_t)row * 64 + l] = hi;
  ((ushort4*)zelo)[(size_t)row * 64 + l] = lo;
  if (l == 0) {
    ws[RSZ_OFF + row] = 1.0f / sqrtf(s);
    ws[SQNZ_OFF + row] = sqrtf(s);
  }
}

// ---- split-MFMA GEMM: 128x128 tile, 4 waves (2x2), 64x64 per wave ----
// dot ~= hi*hi + hi*lo + lo*hi (error <= ~1.3*2^-17*||z||*||e|| ~ 3e-3).
// LDS planes padded: 128 rows x 80B (5 uint4) each -> conflict-free b128.
__global__ __launch_bounds__(256) void vq_gemm(const float* __restrict__ ws,
                                               float* out) {
  __shared__ uint4 lds4[2560];            // Ahi 0 | Alo 640 | Bhi 1280 | Blo 1920
  __shared__ float rszS[128], rseS[128];

  const int t = threadIdx.x;
  const int bx = blockIdx.x & 7;          // 8 code tiles
  const int by = blockIdx.x >> 3;         // 256 row tiles
  const int m0 = by * 128, n0 = bx * 128;
  const int l = t & 63, w = t >> 6;
  const int wr = w >> 1, wc = w & 1;
  const int ln = l & 15, kg = l >> 4;

  const uint4* zehi4 = (const uint4*)out;                       // row stride 32 u4
  const uint4* zelo4 = (const uint4*)((const char*)out + 16777216);
  const uint4* cbhi4 = (const uint4*)((const char*)ws + CBHI_BYTE);
  const uint4* cblo4 = (const uint4*)((const char*)ws + CBLO_BYTE);
  float* sim_out = out + SIM_OFF;

  if (t < 128) rszS[t] = ws[RSZ_OFF + m0 + t];
  else         rseS[t - 128] = ws[RSE_OFF + n0 + (t - 128)];

  f32x4 acc[4][4];
  #pragma unroll
  for (int i = 0; i < 4; ++i)
    #pragma unroll
    for (int j = 0; j < 4; ++j) acc[i][j] = (f32x4){0.f, 0.f, 0.f, 0.f};

  for (int kt = 0; kt < 8; ++kt) {
    __syncthreads();
    #pragma unroll
    for (int i = 0; i < 2; ++i) {
      int f2 = i * 256 + t;
      int r = f2 >> 2, q = f2 & 3;
      int gsrcA = (m0 + r) * 32 + kt * 4 + q;
      int gsrcB = (n0 + r) * 32 + kt * 4 + q;
      int dst = r * 5 + q;
      lds4[dst]        = zehi4[gsrcA];
      lds4[640 + dst]  = zelo4[gsrcA];
      lds4[1280 + dst] = cbhi4[gsrcB];
      lds4[1920 + dst] = cblo4[gsrcB];
    }
    __syncthreads();

    bf16x8 ah[4], al[4], bh[4], bl[4];
    #pragma unroll
    for (int fm = 0; fm < 4; ++fm) {
      int rl = wr * 64 + fm * 16 + ln;
      ah[fm] = *(const bf16x8*)&lds4[rl * 5 + kg];
      al[fm] = *(const bf16x8*)&lds4[640 + rl * 5 + kg];
    }
    #pragma unroll
    for (int fn = 0; fn < 4; ++fn) {
      int cl = wc * 64 + fn * 16 + ln;
      bh[fn] = *(const bf16x8*)&lds4[1280 + cl * 5 + kg];
      bl[fn] = *(const bf16x8*)&lds4[1920 + cl * 5 + kg];
    }
    #pragma unroll
    for (int fm = 0; fm < 4; ++fm)
      #pragma unroll
      for (int fn = 0; fn < 4; ++fn) {
        acc[fm][fn] = __builtin_amdgcn_mfma_f32_16x16x32_bf16(ah[fm], bh[fn], acc[fm][fn], 0, 0, 0);
        acc[fm][fn] = __builtin_amdgcn_mfma_f32_16x16x32_bf16(ah[fm], bl[fn], acc[fm][fn], 0, 0, 0);
        acc[fm][fn] = __builtin_amdgcn_mfma_f32_16x16x32_bf16(al[fm], bh[fn], acc[fm][fn], 0, 0, 0);
      }
  }

  // epilogue: similarity only (C/D: col=l&15, row=(l>>4)*4+reg — m89-verified)
  #pragma unroll
  for (int fm = 0; fm < 4; ++fm)
    #pragma unroll
    for (int fn = 0; fn < 4; ++fn) {
      f32x4 v = acc[fm][fn];
      int cl = wc * 64 + fn * 16 + ln;
      int col = n0 + cl;
      float se = rseS[cl];
      int rbase = wr * 64 + fm * 16 + kg * 4;
      #pragma unroll
      for (int r = 0; r < 4; ++r) {
        int rl = rbase + r;
        sim_out[(size_t)(m0 + rl) * 1024 + col] = v[r] * rszS[rl] * se;
      }
    }
}

// ---- pass2: wave per row. Rescan sim row -> approx dist; exact-refine
// (double-precision dot) all candidates within margin; gather z_q, ids,
// commit-norm partial. ----
__global__ __launch_bounds__(256) void vq_pass2(const float* __restrict__ ze,
                                                const float* __restrict__ cb,
                                                const float* __restrict__ ws,
                                                float* __restrict__ out,
                                                float* __restrict__ wspart) {
  __shared__ float ps[4];
  const int t = threadIdx.x, w = t >> 6, l = t & 63;
  const int row = blockIdx.x * 4 + w;
  const float* sim = out + SIM_OFF;
  const float4* cb4 = (const float4*)cb;

  float4 z4 = ((const float4*)ze)[(size_t)row * 64 + l];
  float sqn = ws[SQNZ_OFF + row];

  // approx dists for this lane's 16 codes (cid = 16l + 4j + e)
  float d[16];
  unsigned long long kmin = 0xFFFFFFFFFFFFFFFFull;
  #pragma unroll
  for (int j = 0; j < 4; ++j) {
    float4 s4 = ((const float4*)sim)[(size_t)row * 256 + l * 4 + j];
    float4 ne4 = ((const float4*)(ws + NE_OFF))[l * 4 + j];
    float4 sq4 = ((const float4*)(ws + SQNE_OFF))[l * 4 + j];
    const float* sp = (const float*)&s4;
    const float* np = (const float*)&ne4;
    const float* qp = (const float*)&sq4;
    #pragma unroll
    for (int e = 0; e < 4; ++e) {
      float dist = np[e] - 2.0f * (sp[e] * sqn * qp[e]);
      d[j * 4 + e] = dist;
      unsigned long long k = packkey(dist, l * 16 + j * 4 + e);
      kmin = k < kmin ? k : kmin;
    }
  }
  #pragma unroll
  for (int m = 1; m < 64; m <<= 1) {
    unsigned long long o = __shfl_xor(kmin, m, 64);
    kmin = o < kmin ? o : kmin;
  }
  unsigned du = (unsigned)(kmin >> 32);
  du ^= (du & 0x80000000u) ? 0x80000000u : 0xFFFFFFFFu;  // un-map
  float thr = __uint_as_float(du) + 0.5f;                 // margin >> split error bound

  unsigned lm = 0;
  #pragma unroll
  for (int e = 0; e < 16; ++e) lm |= (d[e] <= thr) ? (1u << e) : 0u;

  // exact refine over candidates, ascending cid => first-occurrence ties
  double bestd = 1e300;
  int bestid = 0;
  unsigned long long wb = __ballot(lm != 0);
  while (wb) {
    int src = __ffsll(wb) - 1;
    wb &= wb - 1;
    unsigned m = (unsigned)__shfl((int)lm, src, 64);
    while (m) {
      int e = __ffs(m) - 1;
      m &= m - 1;
      int cid = src * 16 + e;
      float4 c4 = cb4[(size_t)cid * 64 + l];
      double p = (double)z4.x * c4.x + (double)z4.y * c4.y +
                 (double)z4.z * c4.z + (double)z4.w * c4.w;
      #pragma unroll
      for (int mm = 1; mm < 64; mm <<= 1) p += __shfl_xor(p, mm, 64);
      double dist = (double)ws[NE_OFF + cid] - 2.0 * p;
      if (dist < bestd) { bestd = dist; bestid = cid; }
    }
  }

  // gather z_q, commit norm, ids
  float4 q4 = cb4[(size_t)bestid * 64 + l];
  ((float4*)out)[(size_t)row * 64 + l] = q4;
  float dx = z4.x - q4.x, dy = z4.y - q4.y, dz = z4.z - q4.z, dw = z4.w - q4.w;
  float s = dx * dx + dy * dy + dz * dz + dw * dw;
  #pragma unroll
  for (int m = 1; m < 64; m <<= 1) s += __shfl_xor(s, m, 64);
  if (l == 0) {
    ps[w] = sqrtf(s);
    out[IDS_OFF + row] = (float)bestid;
  }
  __syncthreads();
  if (t == 0) wspart[blockIdx.x] = ps[0] + ps[1] + ps[2] + ps[3];
}

__global__ __launch_bounds__(256) void vq_loss(const float* __restrict__ wspart,
                                               float* __restrict__ out) {
  __shared__ float red[4];
  int t = threadIdx.x;
  float s = 0.f;
  #pragma unroll
  for (int k = 0; k < 32; ++k) s += wspart[t + 256 * k];
  #pragma unroll
  for (int m = 1; m < 64; m <<= 1) s += __shfl_xor(s, m, 64);
  if ((t & 63) == 0) red[t >> 6] = s;
  __syncthreads();
  if (t == 0)
    out[LOSS_OFF] = (red[0] + red[1] + red[2] + red[3]) * (1.25f / 32768.0f);
}

extern "C" void kernel_launch(void* const* d_in, const int* in_sizes, int n_in,
                              void* d_out, int out_size, void* d_ws, size_t ws_size,
                              hipStream_t stream) {
  const float* ze = (const float*)d_in[0];
  const float* cb = (const float*)d_in[1];
  float* out = (float*)d_out;
  float* ws = (float*)d_ws;

  cb_prep<<<256, 256, 0, stream>>>(cb, ws);
  ze_prep<<<8192, 256, 0, stream>>>(ze, ws, out);
  vq_gemm<<<2048, 256, 0, stream>>>(ws, out);
  vq_pass2<<<8192, 256, 0, stream>>>(ze, cb, ws, out, ws + PART_OFF);
  vq_loss<<<1, 256, 0, stream>>>(ws + PART_OFF, out);
}